// Round 11
// baseline (509.824 us; speedup 1.0000x reference)
//
#include <hip/hip_runtime.h>
#include <stdint.h>
#include <math.h>

#define HIDN 512
#define NHEAD 4
#define DHEAD 128
#define BATCH 16
#define SEQ 1024
#define NNODE 1026
#define MROWS (BATCH * NNODE)   // 16416
#define MPAD 16640              // 65 * 256 (node rows padded for 256-row tiles)
#define MTOK (BATCH * SEQ)      // 16384
#define FFD 2048
#define JCH 114                 // gl-attn j-chunk (9 * 114 = 1026)

typedef short bf16x8 __attribute__((ext_vector_type(8)));
typedef float f32x4 __attribute__((ext_vector_type(4)));

__device__ __forceinline__ float bf2f(ushort u) {
    union { uint32_t i; float f; } v; v.i = ((uint32_t)u) << 16; return v.f;
}
__device__ __forceinline__ ushort f2bf(float f) {
    uint32_t x = __float_as_uint(f);
    return (ushort)((x + 0x7fffu + ((x >> 16) & 1u)) >> 16);
}
// fast gelu: erf via Abramowitz-Stegun 7.1.26 (max abs err 1.5e-7)
__device__ __forceinline__ float gelu(float v) {
    float z = v * 0.70710678118654752f;
    float az = fabsf(z);
    float t = __builtin_amdgcn_rcpf(1.f + 0.3275911f * az);
    float y = ((((1.061405429f * t - 1.453152027f) * t + 1.421413741f) * t
                - 0.284496736f) * t + 0.254829592f) * t;
    float e = __expf(-az * az);
    float erfv = 1.f - y * e;
    erfv = (z >= 0.f) ? erfv : -erfv;
    return 0.5f * v * (1.f + erfv);
}

// ---------------------------------------------------------------- build nodes: fp32 in -> bf16 node buffer (MPAD rows, zero-padded)
__global__ __launch_bounds__(256) void k_build_nodes(
    const float* __restrict__ g, const float* __restrict__ tok,
    const float* __restrict__ l, ushort* __restrict__ nb)
{
    int idx = blockIdx.x * 256 + threadIdx.x;       // MPAD*HIDN total
    int r = idx >> 9, c = idx & 511;
    float u = 0.f;
    if (r < MROWS) {
        int b = r / NNODE;
        int n = r - b * NNODE;
        if (n == 0)            u = g[b * HIDN + c];
        else if (n <= SEQ)     u = tok[((size_t)b * SEQ + (n - 1)) * HIDN + c];
        else                   u = l[b * HIDN + c];
    }
    nb[idx] = f2bf(u);
}

// ---------------------------------------------------------------- fp32 -> bf16 flat convert
__global__ __launch_bounds__(256) void k_cvt(
    const float* __restrict__ in, ushort* __restrict__ out, int n)
{
    int idx = blockIdx.x * 256 + threadIdx.x;
    if (idx < n) out[idx] = f2bf(in[idx]);
}

// ---------------------------------------------------------------- transpose fp32 -> bf16
__global__ __launch_bounds__(256) void k_transpose(
    const float* __restrict__ in, ushort* __restrict__ out, int R, int C)
{
    __shared__ float t[32][33];
    int x = blockIdx.x * 32 + threadIdx.x;
    int y0 = blockIdx.y * 32;
    for (int dy = threadIdx.y; dy < 32; dy += 8)
        t[dy][threadIdx.x] = in[(size_t)(y0 + dy) * C + x];
    __syncthreads();
    int ox = y0 + threadIdx.x;
    int oy0 = blockIdx.x * 32;
    for (int dy = threadIdx.y; dy < 32; dy += 8)
        out[(size_t)(oy0 + dy) * R + ox] = f2bf(t[threadIdx.x][dy]);
}

// ---------------------------------------------------------------- 256xNB MFMA GEMM
// NB=256 (FFN1), NB=128 (FFN2 + node-proj). 512 threads (8 waves, 2M x 4N).
// Double-buffered LDS: NB=256 -> 128 KB, NB=128 -> 96 KB.
// Bijective XCD remap (works for any nwg — node-proj grid is 260).
// Reads kk-outer/fi0-major: af[4] loaded once per (kk,fi0), reused across fj0.
// No setprio (round-10 evidence: FFN1 70->77 with it; m190: lockstep null/neg).
// mode 1: Cb bf16 = gelu(A*B + bias) (amap on A rows)
// mode 3 (NB=128 only): Cb bf16 = A*B + fused sq/sk (Cf=sqb, sk at +MPAD*4,
//         bias=gat_a head vectors), row-guarded at mguard
// mode 0: Cf fp32 = A*B
#define QK 64

template<int NB>
__global__ __launch_bounds__(512) void k_g256(
    const ushort* __restrict__ A, const ushort* __restrict__ Bt,
    float* __restrict__ Cf, ushort* __restrict__ Cb,
    const float* __restrict__ bias,
    int N, int K, int mode, int amap, int mguard)
{
    extern __shared__ ushort smem[];
    constexpr int FJ   = NB / 64;          // fj frags per wave (4 or 2)
    constexpr int BCH  = NB / 64;          // B 8-row chunks staged per wave
    constexpr int BUFU = 16384 + NB * 64;  // ushorts per buffer
    constexpr int CW   = NB / 4;           // cols per wave / per epi-thread
    constexpr int CMSK = CW - 1;           // f4-chunk XOR mask in epilogue

    int tid = threadIdx.x;
    int lane = tid & 63;
    int wave = tid >> 6;                  // 0..7
    int wr = wave >> 2;                   // 0..1  M-half
    int wc = wave & 3;                    // 0..3  N-quarter

    // ---- bijective XCD remap (valid for any nwg; identical to the simple
    // swizzle when nwg % 8 == 0)
    int GX = gridDim.x;
    int nwg = GX * gridDim.y;
    int bid = blockIdx.y * GX + blockIdx.x;
    int q8 = nwg >> 3, r8 = nwg & 7;
    int xcd = bid & 7, pos = bid >> 3;
    int cbase = (xcd < r8) ? xcd * (q8 + 1) : r8 * (q8 + 1) + (xcd - r8) * q8;
    int wk = cbase + pos;
    int m0 = (wk / GX) * 256;
    int n0 = (wk % GX) * NB;

    f32x4 acc[8][FJ];
#pragma unroll
    for (int i = 0; i < 8; ++i)
#pragma unroll
        for (int j = 0; j < FJ; ++j) acc[i][j] = (f32x4){0.f, 0.f, 0.f, 0.f};

    int lr = lane >> 3;                   // 0..7 row within 8-row chunk
    int gco = ((lane & 7) ^ lr) * 8;      // pre-swizzled global col offset

    const ushort* pA[4];
    const ushort* pB[BCH];
#pragma unroll
    for (int u = 0; u < 4; ++u) {
        int q = wave * 4 + u;             // 0..31 (256 A rows)
        int grA = m0 + q * 8 + lr;
        if (amap) grA = grA + 2 * (grA >> 10) + 1;
        pA[u] = A + (size_t)grA * K + gco;
    }
#pragma unroll
    for (int u = 0; u < BCH; ++u) {
        int q = wave * BCH + u;           // 0..NB/8-1 (NB B rows)
        int grB = n0 + q * 8 + lr;
        pB[u] = Bt + (size_t)grB * K + gco;
    }

    auto stage = [&](int buf) {
        ushort* sA = smem + buf * BUFU;
        ushort* sB = sA + 16384;
#pragma unroll
        for (int u = 0; u < 4; ++u) {
            int q = wave * 4 + u;
            __builtin_amdgcn_global_load_lds(
                (const __attribute__((address_space(1))) void*)pA[u],
                (__attribute__((address_space(3))) void*)&sA[q * 512], 16, 0, 0);
            pA[u] += QK;
        }
#pragma unroll
        for (int u = 0; u < BCH; ++u) {
            int q = wave * BCH + u;
            __builtin_amdgcn_global_load_lds(
                (const __attribute__((address_space(1))) void*)pB[u],
                (__attribute__((address_space(3))) void*)&sB[q * 512], 16, 0, 0);
            pB[u] += QK;
        }
    };

    const int nk = K / QK;
    stage(0);
    __syncthreads();                      // tile 0 resident

    int rr = lane & 7;
    int rhi = (lane & 15) >> 3;
    for (int t = 0; t < nk; ++t) {
        if (t + 1 < nk) stage((t + 1) & 1);   // into other buffer — safe

        const ushort* sAr = smem + (t & 1) * BUFU;
        const ushort* sBr = sAr + 16384;
#pragma unroll
        for (int kk = 0; kk < 2; ++kk) {
            int c4 = kk * 4 + (lane >> 4);
            int swz = rr * 64 + ((c4 ^ rr) << 3);
#pragma unroll
            for (int fi0 = 0; fi0 < 8; fi0 += 4) {
                bf16x8 af[4];
#pragma unroll
                for (int i = 0; i < 4; ++i) {
                    int qA = wr * 16 + (fi0 + i) * 2 + rhi;
                    af[i] = *reinterpret_cast<const bf16x8*>(&sAr[qA * 512 + swz]);
                }
#pragma unroll
                for (int fj0 = 0; fj0 < FJ; fj0 += 2) {
                    bf16x8 bfr[2];
#pragma unroll
                    for (int j = 0; j < 2; ++j) {
                        int qB = wc * (NB / 32) + (fj0 + j) * 2 + rhi;
                        bfr[j] = *reinterpret_cast<const bf16x8*>(&sBr[qB * 512 + swz]);
                    }
#pragma unroll
                    for (int i = 0; i < 4; ++i)
#pragma unroll
                        for (int j = 0; j < 2; ++j)
                            acc[fi0 + i][fj0 + j] = __builtin_amdgcn_mfma_f32_16x16x32_bf16(
                                af[i], bfr[j], acc[fi0 + i][fj0 + j], 0, 0, 0);
                }
            }
        }
        __syncthreads();                  // own stage landed + all reads done
    }

    // -------- epilogue: 2 passes of 128 rows via LDS f32 tile [128][NB]
    float* sC = (float*)smem;
    int rb = (lane >> 4) * 4;
    int cb = lane & 15;
    int lrow = tid >> 2;                  // 0..127
    int lcol = (tid & 3) * CW;
#pragma unroll
    for (int pass = 0; pass < 2; ++pass) {
        if (wr == pass) {
#pragma unroll
            for (int fi = 0; fi < 8; ++fi)
#pragma unroll
                for (int fj = 0; fj < FJ; ++fj)
#pragma unroll
                    for (int rg = 0; rg < 4; ++rg) {
                        int row = fi * 16 + rb + rg;
                        int col = wc * CW + fj * 16 + cb;
                        sC[row * NB + ((((col >> 2) ^ (row & 7)) & CMSK) << 2) + (col & 3)] =
                            acc[fi][fj][rg];
                    }
        }
        __syncthreads();
        int gm = m0 + pass * 128 + lrow;
        if (mode == 1) {
            uint4* dst = (uint4*)(Cb + (size_t)gm * N + n0 + lcol);
#pragma unroll
            for (int g = 0; g < CW / 8; ++g) {
                int col = lcol + g * 8;
                float4 a = *(const float4*)&sC[lrow * NB + ((((col >> 2) ^ (lrow & 7)) & CMSK) << 2)];
                float4 b = *(const float4*)&sC[lrow * NB + (((((col + 4) >> 2) ^ (lrow & 7)) & CMSK) << 2)];
                const float* bp = bias + n0 + col;
                float s0 = gelu(a.x + bp[0]), s1 = gelu(a.y + bp[1]);
                float s2 = gelu(a.z + bp[2]), s3 = gelu(a.w + bp[3]);
                float s4 = gelu(b.x + bp[4]), s5 = gelu(b.y + bp[5]);
                float s6 = gelu(b.z + bp[6]), s7 = gelu(b.w + bp[7]);
                uint4 w;
                w.x = (uint32_t)f2bf(s0) | ((uint32_t)f2bf(s1) << 16);
                w.y = (uint32_t)f2bf(s2) | ((uint32_t)f2bf(s3) << 16);
                w.z = (uint32_t)f2bf(s4) | ((uint32_t)f2bf(s5) << 16);
                w.w = (uint32_t)f2bf(s6) | ((uint32_t)f2bf(s7) << 16);
                dst[g] = w;
            }
        } else if (mode == 3) {
            if constexpr (NB == 128) {
                // node-proj epilogue: bf16 C + fused sq/sk. This n-block is
                // exactly head n0>>7; this thread covers dims lcol..lcol+31.
                if (gm < mguard) {
                    float v[32];
#pragma unroll
                    for (int e4 = 0; e4 < 8; ++e4) {
                        int col = lcol + e4 * 4;
                        float4 t = *(const float4*)&sC[lrow * NB + ((((col >> 2) ^ (lrow & 7)) & CMSK) << 2)];
                        v[e4 * 4 + 0] = t.x; v[e4 * 4 + 1] = t.y;
                        v[e4 * 4 + 2] = t.z; v[e4 * 4 + 3] = t.w;
                    }
                    int head = n0 >> 7;
                    const float* a1 = bias + head * 256 + lcol;
                    const float* a2 = a1 + 128;
                    float s1 = 0.f, s2 = 0.f;
#pragma unroll
                    for (int j = 0; j < 32; ++j) {
                        s1 += v[j] * a1[j];
                        s2 += v[j] * a2[j];
                    }
                    s1 += __shfl_xor(s1, 1); s1 += __shfl_xor(s1, 2);
                    s2 += __shfl_xor(s2, 1); s2 += __shfl_xor(s2, 2);
                    if ((tid & 3) == 0) {
                        Cf[gm * 4 + head] = s1;                    // sq
                        Cf[(size_t)MPAD * 4 + gm * 4 + head] = s2; // sk
                    }
                    uint4* dst = (uint4*)(Cb + (size_t)gm * N + n0 + lcol);
#pragma unroll
                    for (int q2 = 0; q2 < 4; ++q2) {
                        uint4 w;
                        w.x = (uint32_t)f2bf(v[q2 * 8 + 0]) | ((uint32_t)f2bf(v[q2 * 8 + 1]) << 16);
                        w.y = (uint32_t)f2bf(v[q2 * 8 + 2]) | ((uint32_t)f2bf(v[q2 * 8 + 3]) << 16);
                        w.z = (uint32_t)f2bf(v[q2 * 8 + 4]) | ((uint32_t)f2bf(v[q2 * 8 + 5]) << 16);
                        w.w = (uint32_t)f2bf(v[q2 * 8 + 6]) | ((uint32_t)f2bf(v[q2 * 8 + 7]) << 16);
                        dst[q2] = w;
                    }
                }
            }
        } else {
            float4* dst = (float4*)(Cf + (size_t)gm * N + n0 + lcol);
#pragma unroll
            for (int e4 = 0; e4 < CW / 4; ++e4) {
                int col = lcol + e4 * 4;
                float4 tv = *(const float4*)&sC[lrow * NB + ((((col >> 2) ^ (lrow & 7)) & CMSK) << 2)];
                dst[e4] = tv;
            }
        }
        __syncthreads();
    }
}

// ---------------------------------------------------------------- token attention + elu + residual + LN (1 wave / token, 4 waves / block)
__global__ __launch_bounds__(256) void k_attn_token(
    const ushort* __restrict__ P, const float* __restrict__ sq, const float* __restrict__ sk,
    const float* __restrict__ am, const int* __restrict__ last,
    const float* __restrict__ gam, const float* __restrict__ bet,
    ushort* __restrict__ nb)
{
    int wid = blockIdx.x * 4 + (threadIdx.x >> 6);
    int tokid = ((wid & 7) << 11) | (wid >> 3);
    int b = tokid >> 10, i = tokid & 1023;
    int lane = threadIdx.x & 63;
    int hh = lane >> 4;
    int base = b * NNODE;
    int qrow = base + 1 + i;

    int kr[13];
    int val[13];
    int rowok = am[b * SEQ + i] > 0.f ? 1 : 0;
    kr[0] = base; val[0] = rowok;
#pragma unroll
    for (int s = 0; s < 11; ++s) {
        int t = i - 5 + s;
        int inb = (t >= 0) && (t <= SEQ - 1);
        int tt = inb ? t : 0;
        int v = inb && rowok && (am[b * SEQ + tt] > 0.f);
        kr[1 + s] = base + 1 + tt;
        val[1 + s] = v;
    }
    kr[12] = base + SEQ + 1;
    val[12] = (rowok && (i >= last[b])) ? 1 : 0;

    float sqv = sq[qrow * 4 + hh];
    float sc[13];
    float mx = -1e30f;
#pragma unroll
    for (int t = 0; t < 13; ++t) {
        float s = 0.f;
        if (val[t]) {
            s = sqv + sk[kr[t] * 4 + hh];
            s = s >= 0.f ? s : 0.2f * s;
            mx = fmaxf(mx, s);
        }
        sc[t] = s;
    }
    float den = 0.f;
#pragma unroll
    for (int t = 0; t < 13; ++t) {
        float ev = 0.f;
        if (val[t]) ev = expf(sc[t] - mx);
        sc[t] = ev; den += ev;
    }
    float inv = (den > 1e-30f && den < 1e30f) ? 1.f / den : 0.f;

    int o0 = lane * 8;
    float accv[8] = {0.f, 0.f, 0.f, 0.f, 0.f, 0.f, 0.f, 0.f};
#pragma unroll
    for (int t = 0; t < 13; ++t) {
        if (val[t]) {
            float wgt = sc[t] * inv;
            const ushort* pv = P + (size_t)kr[t] * HIDN + o0;
#pragma unroll
            for (int d = 0; d < 8; ++d) accv[d] += wgt * bf2f(pv[d]);
        }
    }

    ushort* nrow = nb + (size_t)qrow * HIDN + o0;
    float x[8], s1 = 0.f, s2 = 0.f;
#pragma unroll
    for (int d = 0; d < 8; ++d) {
        float v = accv[d];
        v = v > 0.f ? v : expf(v) - 1.f;   // elu
        v += bf2f(nrow[d]);                // residual
        x[d] = v; s1 += v; s2 += v * v;
    }
#pragma unroll
    for (int off = 32; off; off >>= 1) { s1 += __shfl_xor(s1, off); s2 += __shfl_xor(s2, off); }
    float mean = s1 * (1.f / 512.f);
    float var = s2 * (1.f / 512.f) - mean * mean; var = fmaxf(var, 0.f);
    float rn = rsqrtf(var + 1e-5f);
#pragma unroll
    for (int d = 0; d < 8; ++d) {
        float y = (x[d] - mean) * rn * gam[o0 + d] + bet[o0 + d];
        nrow[d] = f2bf(y);
    }
}

// ---------------------------------------------------------------- g/l attention, split version
__global__ __launch_bounds__(256) void k_glsm(
    const float* __restrict__ sq, const float* __restrict__ sk,
    const int* __restrict__ last,
    float* __restrict__ ebuf, float* __restrict__ einv)
{
    __shared__ float red[1024];
    int rw = blockIdx.x, b = rw >> 1, isl = rw & 1;
    int base = b * NNODE;
    int qrow = base + (isl ? (SEQ + 1) : 0);
    int lastb = last[b];
    int tid = threadIdx.x;

    float sqh[4];
#pragma unroll
    for (int h = 0; h < 4; ++h) sqh[h] = sq[qrow * 4 + h];

    float mx[4] = {-1e30f, -1e30f, -1e30f, -1e30f};
    for (int j = tid; j < NNODE; j += 256) {
        bool ok = !isl || (j == 0 || j == SEQ + 1 || (j >= lastb + 1 && j <= SEQ));
        if (ok) {
#pragma unroll
            for (int h = 0; h < 4; ++h) {
                float s = sqh[h] + sk[(base + j) * 4 + h];
                s = s >= 0.f ? s : 0.2f * s;
                mx[h] = fmaxf(mx[h], s);
            }
        }
    }
#pragma unroll
    for (int h = 0; h < 4; ++h) red[tid * 4 + h] = mx[h];
    __syncthreads();
    for (int s = 128; s; s >>= 1) {
        if (tid < s) {
#pragma unroll
            for (int h = 0; h < 4; ++h)
                red[tid * 4 + h] = fmaxf(red[tid * 4 + h], red[(tid + s) * 4 + h]);
        }
        __syncthreads();
    }
#pragma unroll
    for (int h = 0; h < 4; ++h) mx[h] = red[h];
    __syncthreads();

    float sm[4] = {0.f, 0.f, 0.f, 0.f};
    for (int j = tid; j < NNODE; j += 256) {
        bool ok = !isl || (j == 0 || j == SEQ + 1 || (j >= lastb + 1 && j <= SEQ));
#pragma unroll
        for (int h = 0; h < 4; ++h) {
            float v = 0.f;
            if (ok) {
                float s = sqh[h] + sk[(base + j) * 4 + h];
                s = s >= 0.f ? s : 0.2f * s;
                v = expf(s - mx[h]);
            }
            ebuf[((size_t)rw * NNODE + j) * 4 + h] = v;
            sm[h] += v;
        }
    }
#pragma unroll
    for (int h = 0; h < 4; ++h) red[tid * 4 + h] = sm[h];
    __syncthreads();
    for (int s = 128; s; s >>= 1) {
        if (tid < s) {
#pragma unroll
            for (int h = 0; h < 4; ++h) red[tid * 4 + h] += red[(tid + s) * 4 + h];
        }
        __syncthreads();
    }
    if (tid < 4) {
        float den = red[tid];
        einv[rw * 4 + tid] = (den > 1e-30f && den < 1e30f) ? 1.f / den : 0.f;
    }
}

__global__ __launch_bounds__(256) void k_glpv(
    const ushort* __restrict__ P, const float* __restrict__ ebuf,
    float* __restrict__ pout2)
{
    __shared__ float es[JCH * 4];
    int p = blockIdx.x, rw = blockIdx.y;
    int b = rw >> 1;
    int base = b * NNODE;
    int tid = threadIdx.x;
    for (int t = tid; t < JCH * 4; t += 256)
        es[t] = ebuf[((size_t)rw * NNODE + p * JCH) * 4 + t];
    __syncthreads();
    int o0 = tid, o1 = tid + 256;
    int h0 = o0 >> 7, h1 = o1 >> 7;
    const ushort* Pb = P + (size_t)(base + p * JCH) * HIDN;
    float a0 = 0.f, a1 = 0.f;
    for (int j = 0; j < JCH; ++j) {
        const ushort* pr = Pb + (size_t)j * HIDN;
        a0 += es[j * 4 + h0] * bf2f(pr[o0]);
        a1 += es[j * 4 + h1] * bf2f(pr[o1]);
    }
    float* o = pout2 + ((size_t)rw * 9 + p) * HIDN;
    o[o0] = a0;
    o[o1] = a1;
}

__global__ __launch_bounds__(256) void k_glred(
    const float* __restrict__ pout2, const float* __restrict__ einv,
    const float* __restrict__ gam, const float* __restrict__ bet,
    ushort* __restrict__ nb)
{
    __shared__ float red[512];
    int rw = blockIdx.x, b = rw >> 1, isl = rw & 1;
    size_t qrow = (size_t)b * NNODE + (isl ? SEQ + 1 : 0);
    int tid = threadIdx.x;
    float xv[2], s1 = 0.f, s2 = 0.f;
#pragma unroll
    for (int u = 0; u < 2; ++u) {
        int o = tid + u * 256;
        int h = o >> 7;
        float acc = 0.f;
#pragma unroll
        for (int p = 0; p < 9; ++p)
            acc += pout2[((size_t)rw * 9 + p) * HIDN + o];
        acc *= einv[rw * 4 + h];
        float v = acc > 0.f ? acc : expf(acc) - 1.f;
        v += bf2f(nb[qrow * HIDN + o]);
        xv[u] = v; s1 += v; s2 += v * v;
    }
    red[tid] = s1;
    __syncthreads();
    for (int s = 128; s; s >>= 1) { if (tid < s) red[tid] += red[tid + s]; __syncthreads(); }
    float mean = red[0] * (1.f / 512.f);
    __syncthreads();
    red[tid] = s2;
    __syncthreads();
    for (int s = 128; s; s >>= 1) { if (tid < s) red[tid] += red[tid + s]; __syncthreads(); }
    float var = red[0] * (1.f / 512.f) - mean * mean; var = fmaxf(var, 0.f);
    float rn = rsqrtf(var + 1e-5f);
#pragma unroll
    for (int u = 0; u < 2; ++u) {
        int o = tid + u * 256;
        float y = (xv[u] - mean) * rn * gam[o] + bet[o];
        nb[qrow * HIDN + o] = f2bf(y);
    }
}

// ---------------------------------------------------------------- g/l FFN, parallel split version
__global__ __launch_bounds__(256) void k_fgl1(
    const ushort* __restrict__ nb, const float* __restrict__ w1,
    float* __restrict__ pmid)
{
    __shared__ float xs[64];
    int p = blockIdx.x, rw = blockIdx.y;
    int b = rw >> 1, isl = rw & 1;
    int idx = isl ? 2 : 0;
    size_t nrow = (size_t)b * NNODE + (isl ? SEQ + 1 : 0);
    int tid = threadIdx.x;
    if (tid < 64) xs[tid] = bf2f(nb[nrow * HIDN + p * 64 + tid]);
    __syncthreads();
    const float* W1 = w1 + (size_t)idx * HIDN * FFD + (size_t)p * 64 * FFD;
    float acc[8] = {0.f, 0.f, 0.f, 0.f, 0.f, 0.f, 0.f, 0.f};
    for (int ii = 0; ii < 64; ++ii) {
        float xv = xs[ii];
        const float* wrow = W1 + (size_t)ii * FFD + tid;
#pragma unroll
        for (int u = 0; u < 8; ++u) acc[u] += xv * wrow[u * 256];
    }
    float* o = pmid + ((size_t)rw * 8 + p) * FFD + tid;
#pragma unroll
    for (int u = 0; u < 8; ++u) o[u * 256] = acc[u];
}

__global__ __launch_bounds__(256) void k_fgl2(
    const float* __restrict__ pmid, const float* __restrict__ b1,
    float* __restrict__ mid)
{
    int g = blockIdx.x * 256 + threadIdx.x;
    int e4 = g * 4;
    int rw = e4 >> 11;
    int m = e4 & 2047;
    int isl = rw & 1;
    int idx = isl ? 2 : 0;
#pragma unroll
    for (int d = 0; d < 4; ++d) {
        float s = 0.f;
#pragma unroll
        for (int p = 0; p < 8; ++p)
            s += pmid[((size_t)rw * 8 + p) * FFD + m + d];
        s += b1[idx * FFD + m + d];
        mid[(size_t)rw * FFD + m + d] = gelu(s);
    }
}

__global__ __launch_bounds__(256) void k_fgl3(
    const float* __restrict__ mid, const float* __restrict__ w2,
    float* __restrict__ pout)
{
    __shared__ float ms[256];
    int p = blockIdx.x, rw = blockIdx.y;
    int isl = rw & 1;
    int idx = isl ? 2 : 0;
    int tid = threadIdx.x;
    ms[tid] = mid[(size_t)rw * FFD + p * 256 + tid];
    __syncthreads();
    const float* W2 = w2 + (size_t)idx * FFD * HIDN + (size_t)p * 256 * HIDN;
    float a0 = 0.f, a1 = 0.f;
    for (int mm = 0; mm < 256; ++mm) {
        float mv = ms[mm];
        const float* wrow = W2 + (size_t)mm * HIDN + tid;
        a0 += mv * wrow[0];
        a1 += mv * wrow[256];
    }
    float* o = pout + ((size_t)rw * 8 + p) * HIDN + tid;
    o[0] = a0;
    o[256] = a1;
}

__global__ __launch_bounds__(256) void k_fgl4(
    const float* __restrict__ pout, const float* __restrict__ b2,
    const ushort* __restrict__ nb,
    const float* __restrict__ og, const float* __restrict__ obt,
    float* __restrict__ out)
{
    __shared__ float red[512];
    int rw = blockIdx.x;
    int b = rw >> 1, isl = rw & 1;
    int idx = isl ? 2 : 0;
    size_t nrow = (size_t)b * NNODE + (isl ? SEQ + 1 : 0);
    int tid = threadIdx.x;
    float xv[2], s1 = 0.f, s2 = 0.f;
#pragma unroll
    for (int u = 0; u < 2; ++u) {
        int o = tid + u * 256;
        float s = 0.f;
#pragma unroll
        for (int p = 0; p < 8; ++p)
            s += pout[((size_t)rw * 8 + p) * HIDN + o];
        s += b2[idx * HIDN + o] + bf2f(nb[nrow * HIDN + o]);
        xv[u] = s; s1 += s; s2 += s * s;
    }
    red[tid] = s1;
    __syncthreads();
    for (int s = 128; s; s >>= 1) { if (tid < s) red[tid] += red[tid + s]; __syncthreads(); }
    float mean = red[0] * (1.f / 512.f);
    __syncthreads();
    red[tid] = s2;
    __syncthreads();
    for (int s = 128; s; s >>= 1) { if (tid < s) red[tid] += red[tid + s]; __syncthreads(); }
    float var = red[0] * (1.f / 512.f) - mean * mean; var = fmaxf(var, 0.f);
    float rn = rsqrtf(var + 1e-5f);
    size_t obase = isl ? ((size_t)8192 + (size_t)MTOK * HIDN + (size_t)b * HIDN)
                       : ((size_t)b * HIDN);
#pragma unroll
    for (int u = 0; u < 2; ++u) {
        int o = tid + u * 256;
        out[obase + o] = (xv[u] - mean) * rn * og[idx * HIDN + o] + obt[idx * HIDN + o];
    }
}

// ---------------------------------------------------------------- final token LN: in-place on Pt (fp32), + bias + residual
__global__ __launch_bounds__(64) void k_ln_final(
    float* __restrict__ Pt, const ushort* __restrict__ nb,
    const float* __restrict__ b2,
    const float* __restrict__ gam, const float* __restrict__ bet)
{
    int r = blockIdx.x, lane = threadIdx.x;
    int nrow = r + 2 * (r >> 10) + 1;
    int o0 = lane * 8;
    float* x = Pt + (size_t)r * HIDN + o0;
    const ushort* res = nb + (size_t)nrow * HIDN + o0;
    float v[8], s1 = 0.f, s2 = 0.f;
#pragma unroll
    for (int d = 0; d < 8; ++d) {
        float t = x[d] + b2[o0 + d] + bf2f(res[d]);
        v[d] = t; s1 += t; s2 += t * t;
    }
#pragma unroll
    for (int off = 32; off; off >>= 1) { s1 += __shfl_xor(s1, off); s2 += __shfl_xor(s2, off); }
    float mean = s1 * (1.f / 512.f);
    float var = s2 * (1.f / 512.f) - mean * mean; var = fmaxf(var, 0.f);
    float rn = rsqrtf(var + 1e-5f);
#pragma unroll
    for (int d = 0; d < 8; ++d)
        x[d] = (v[d] - mean) * rn * gam[o0 + d] + bet[o0 + d];
}

// ================================================================ launch
extern "C" void kernel_launch(void* const* d_in, const int* in_sizes, int n_in,
                              void* d_out, int out_size, void* d_ws, size_t ws_size,
                              hipStream_t stream)
{
    (void)in_sizes; (void)n_in; (void)out_size; (void)ws_size;
    const float* g_emb   = (const float*)d_in[0];
    const float* tok_emb = (const float*)d_in[1];
    const float* l_emb   = (const float*)d_in[2];
    const float* am      = (const float*)d_in[3];
    const int*   last    = (const int*)d_in[4];
    const float* gat_W   = (const float*)d_in[5];
    const float* gat_a   = (const float*)d_in[6];
    const float* ln_g    = (const float*)d_in[7];
    const float* ln_b    = (const float*)d_in[8];
    const float* ffn_w1  = (const float*)d_in[9];
    const float* ffn_b1  = (const float*)d_in[10];
    const float* ffn_w2  = (const float*)d_in[11];
    const float* ffn_b2  = (const float*)d_in[12];
    const float* oln_g   = (const float*)d_in[13];
    const float* oln_b   = (const float*)d_in[14];
    float* out = (float*)d_out;

    // workspace ~98 MiB (harness poisons ~268 MB of ws).
    char* w = (char*)d_ws;
    ushort* nodes_b = (ushort*)w; w += (size_t)MPAD * HIDN * 2;      // 17.0 MB (16640 rows)
    char*   scratch = w;          w += (size_t)8 * 1024 * 1024;      //  8.0 MB (g/l scratch)
    ushort* w1t     = (ushort*)w; w += (size_t)FFD * HIDN * 2;       //  2.1 MB
    ushort* w2t     = (ushort*)w; w += (size_t)FFD * HIDN * 2;       //  2.1 MB
    ushort* gatWb   = (ushort*)w; w += (size_t)2 * HIDN * HIDN * 2;  //  1.0 MB
    float*  sqb     = (float*)w;  w += (size_t)MPAD * 4 * 4;         //  0.27 MB (sq)
    float*  skb     = (float*)w;  w += (size_t)MPAD * 4 * 4;         //  0.27 MB (sk = sqb + MPAD*4)
    ushort* Hmid    = (ushort*)w; w += (size_t)MTOK * FFD * 2;       // 67.1 MB (full FFN mid)

    // g/l FFN scratch (post-layers)
    float* pmid = (float*)scratch;
    float* mid  = pmid + (size_t)32 * 8 * FFD;
    float* pout = mid + (size_t)32 * FFD;
    // g/l attention scratch (at scratch + 3 MB; during layers)
    float* ebuf  = (float*)(scratch + (size_t)3 * 1024 * 1024);
    float* einv  = ebuf + (size_t)32 * NNODE * 4;
    float* pout2 = einv + 128;

    // P (node projections) aliases d_out (dead before outputs written).
    ushort* P = (ushort*)out;
    float* Pt = out + 8192;

    k_build_nodes<<<MPAD * HIDN / 256, 256, 0, stream>>>(g_emb, tok_emb, l_emb, nodes_b);
    k_cvt<<<(2 * HIDN * HIDN) / 256, 256, 0, stream>>>(gat_W, gatWb, 2 * HIDN * HIDN);
    k_transpose<<<dim3(FFD / 32, HIDN / 32), dim3(32, 8), 0, stream>>>(ffn_w1 + (size_t)HIDN * FFD, w1t, HIDN, FFD);
    k_transpose<<<dim3(HIDN / 32, FFD / 32), dim3(32, 8), 0, stream>>>(ffn_w2 + (size_t)FFD * HIDN, w2t, FFD, HIDN);

    for (int k = 0; k < 2; ++k) {
        // node-proj on the 256x128 kernel: grid (4, 65) = 260 blocks (full
        // machine), fused sq/sk epilogue, row-guarded at MROWS.
        k_g256<128><<<dim3(HIDN / 128, MPAD / 256), 512, 98304, stream>>>(
            nodes_b, gatWb + (size_t)k * HIDN * HIDN, sqb, P,
            gat_a + k * NHEAD * 2 * DHEAD,
            HIDN, HIDN, /*mode*/3, /*amap*/0, MROWS);
        k_attn_token<<<MTOK / 4, 256, 0, stream>>>(P, sqb, skb, am, last,
                                                   ln_g + k * HIDN, ln_b + k * HIDN, nodes_b);
        k_glsm<<<32, 256, 0, stream>>>(sqb, skb, last, ebuf, einv);
        k_glpv<<<dim3(9, 32), 256, 0, stream>>>(P, ebuf, pout2);
        k_glred<<<32, 256, 0, stream>>>(pout2, einv, ln_g + k * HIDN, ln_b + k * HIDN, nodes_b);
    }

    // g/l FFN (parallel split) — P (= d_out) dead from here.
    k_fgl1<<<dim3(8, 32), 256, 0, stream>>>(nodes_b, ffn_w1, pmid);
    k_fgl2<<<64, 256, 0, stream>>>(pmid, ffn_b1, mid);
    k_fgl3<<<dim3(8, 32), 256, 0, stream>>>(mid, ffn_w2, pout);
    k_fgl4<<<32, 256, 0, stream>>>(pout, ffn_b2, nodes_b, oln_g, oln_b, out);

    // token FFN. FFN1: 256x256 tile, 512 blocks.
    k_g256<256><<<dim3(FFD / 256, MTOK / 256), 512, 131072, stream>>>(
        nodes_b, w1t, nullptr, Hmid, ffn_b1 + FFD, FFD, HIDN, /*mode*/1, /*amap*/1, MTOK);
    // FFN2: 256x128 tile, 256 blocks (full machine).
    k_g256<128><<<dim3(HIDN / 128, MTOK / 256), 512, 98304, stream>>>(
        Hmid, w2t, Pt, nullptr, nullptr, HIDN, FFD, /*mode*/0, /*amap*/0, MTOK);
    k_ln_final<<<MTOK, 64, 0, stream>>>(Pt, nodes_b, ffn_b2 + HIDN, oln_g + HIDN, oln_b + HIDN);
}

// Round 12
// 472.196 us; speedup vs baseline: 1.0797x; 1.0797x over previous
//
#include <hip/hip_runtime.h>
#include <stdint.h>
#include <math.h>

#define HIDN 512
#define NHEAD 4
#define DHEAD 128
#define BATCH 16
#define SEQ 1024
#define NNODE 1026
#define MROWS (BATCH * NNODE)   // 16416
#define MPAD 16512              // 129 * 128
#define MTOK (BATCH * SEQ)      // 16384
#define FFD 2048
#define JCH 114                 // gl-attn j-chunk (9 * 114 = 1026)

typedef short bf16x8 __attribute__((ext_vector_type(8)));
typedef float f32x4 __attribute__((ext_vector_type(4)));

__device__ __forceinline__ float bf2f(ushort u) {
    union { uint32_t i; float f; } v; v.i = ((uint32_t)u) << 16; return v.f;
}
__device__ __forceinline__ ushort f2bf(float f) {
    uint32_t x = __float_as_uint(f);
    return (ushort)((x + 0x7fffu + ((x >> 16) & 1u)) >> 16);
}
// fast gelu: erf via Abramowitz-Stegun 7.1.26 (max abs err 1.5e-7)
__device__ __forceinline__ float gelu(float v) {
    float z = v * 0.70710678118654752f;
    float az = fabsf(z);
    float t = __builtin_amdgcn_rcpf(1.f + 0.3275911f * az);
    float y = ((((1.061405429f * t - 1.453152027f) * t + 1.421413741f) * t
                - 0.284496736f) * t + 0.254829592f) * t;
    float e = __expf(-az * az);
    float erfv = 1.f - y * e;
    erfv = (z >= 0.f) ? erfv : -erfv;
    return 0.5f * v * (1.f + erfv);
}
// swizzled index into 64x128 f32 epilogue tile (float4-granular XOR)
__device__ __forceinline__ int cswz(int row, int col) {
    return row * 128 + ((((col >> 2) ^ (row & 7)) & 31) << 2) + (col & 3);
}

// ---------------------------------------------------------------- build nodes: fp32 in -> bf16 node buffer
__global__ __launch_bounds__(256) void k_build_nodes(
    const float* __restrict__ g, const float* __restrict__ tok,
    const float* __restrict__ l, ushort* __restrict__ nb)
{
    int idx = blockIdx.x * 256 + threadIdx.x;       // MPAD*HIDN total
    int r = idx >> 9, c = idx & 511;
    float u = 0.f;
    if (r < MROWS) {
        int b = r / NNODE;
        int n = r - b * NNODE;
        if (n == 0)            u = g[b * HIDN + c];
        else if (n <= SEQ)     u = tok[((size_t)b * SEQ + (n - 1)) * HIDN + c];
        else                   u = l[b * HIDN + c];
    }
    nb[idx] = f2bf(u);
}

// ---------------------------------------------------------------- fp32 -> bf16 flat convert
__global__ __launch_bounds__(256) void k_cvt(
    const float* __restrict__ in, ushort* __restrict__ out, int n)
{
    int idx = blockIdx.x * 256 + threadIdx.x;
    if (idx < n) out[idx] = f2bf(in[idx]);
}

// ---------------------------------------------------------------- transpose fp32 -> bf16
__global__ __launch_bounds__(256) void k_transpose(
    const float* __restrict__ in, ushort* __restrict__ out, int R, int C)
{
    __shared__ float t[32][33];
    int x = blockIdx.x * 32 + threadIdx.x;
    int y0 = blockIdx.y * 32;
    for (int dy = threadIdx.y; dy < 32; dy += 8)
        t[dy][threadIdx.x] = in[(size_t)(y0 + dy) * C + x];
    __syncthreads();
    int ox = y0 + threadIdx.x;
    int oy0 = blockIdx.x * 32;
    for (int dy = threadIdx.y; dy < 32; dy += 8)
        out[(size_t)(oy0 + dy) * R + ox] = f2bf(t[threadIdx.x][dy]);
}

// ---------------------------------------------------------------- 128x128 MFMA GEMM (node-proj)
// Round-12: node-proj reverted to this kernel (round-11 evidence: the
// 256x128 template at K=512 / 260 blocks / 1-block-per-CU regressed
// ~+18us per dispatch — 2 near-idle rounds on 4 XCDs + big pro/epilogue
// fraction at nk=8. This 516-block 2-resident config measured best.)
// mode 3: Cb bf16 = A*B, AND fused sq/sk: Cf=sqb (sk at +MPAD*4), bias=gat_a
#define BM 128
#define BN 128
#define BK 64

__global__ __launch_bounds__(256) void k_gemm_bt(
    const ushort* __restrict__ A, const ushort* __restrict__ Bt,
    float* __restrict__ Cf, ushort* __restrict__ Cb,
    const float* __restrict__ bias,
    int N, int K, int ldb, int mode, int amap, int mguard, int first)
{
    __shared__ ushort smem[2 * (BM * BK + BN * BK)];   // 64 KB (2 buffers)
    int tid = threadIdx.x;
    int lane = tid & 63;
    int wave = tid >> 6;
    int wm = wave >> 1, wn = wave & 1;

    // ---- XCD-bijective remap of flat block id (bijective for any nwg)
    int GX = gridDim.x;
    int nwg = GX * gridDim.y;
    int bid = blockIdx.y * GX + blockIdx.x;
    int q = nwg >> 3, r = nwg & 7;
    int xcd = bid & 7, pos = bid >> 3;
    int cbase = (xcd < r) ? xcd * (q + 1) : r * (q + 1) + (xcd - r) * q;
    int wk = cbase + pos;
    int m0 = (wk / GX) * BM;
    int n0 = (wk % GX) * BN;

    f32x4 acc[4][4];
#pragma unroll
    for (int i = 0; i < 4; ++i)
#pragma unroll
        for (int j = 0; j < 4; ++j) acc[i][j] = (f32x4){0.f, 0.f, 0.f, 0.f};

    int lr = lane >> 3;              // row within 8-row chunk
    int gco = ((lane & 7) ^ lr) * 8; // XOR-swizzled col-chunk offset (elements)

    const ushort* pA[4];
    const ushort* pB[4];
#pragma unroll
    for (int u = 0; u < 4; ++u) {
        int qq = wave * 4 + u;           // 0..15 : 8-row chunk id
        int rr8 = qq * 8 + lr;
        int grA = m0 + rr8;
        if (amap) grA = grA + 2 * (grA >> 10) + 1;
        pA[u] = A + (size_t)grA * K + gco;
        int grB = n0 + rr8;
        pB[u] = Bt + (size_t)grB * ldb + gco;
    }

    auto stage = [&](int buf) {
        ushort* sA = smem + buf * (BM * BK + BN * BK);
        ushort* sB = sA + BM * BK;
#pragma unroll
        for (int u = 0; u < 4; ++u) {
            int qq = wave * 4 + u;
            __builtin_amdgcn_global_load_lds(
                (const __attribute__((address_space(1))) void*)pA[u],
                (__attribute__((address_space(3))) void*)&sA[qq * 512], 16, 0, 0);
            __builtin_amdgcn_global_load_lds(
                (const __attribute__((address_space(1))) void*)pB[u],
                (__attribute__((address_space(3))) void*)&sB[qq * 512], 16, 0, 0);
            pA[u] += BK;
            pB[u] += BK;
        }
    };

    const int nk = K / BK;
    stage(0);
    __syncthreads();

    int rr = lane & 7;
    int rhi = (lane & 15) >> 3;
    for (int t = 0; t < nk; ++t) {
        if (t + 1 < nk) stage((t + 1) & 1);

        const ushort* sAr = smem + (t & 1) * (BM * BK + BN * BK);
        const ushort* sBr = sAr + BM * BK;
#pragma unroll
        for (int kk = 0; kk < BK; kk += 32) {
            int c4 = (kk >> 3) + (lane >> 4);          // col-chunk 0..7
            int swz = rr * 64 + ((c4 ^ rr) << 3);
            bf16x8 af[4], bfr[4];
#pragma unroll
            for (int i = 0; i < 4; ++i)
                af[i] = *reinterpret_cast<const bf16x8*>(&sAr[(wm * 8 + i * 2 + rhi) * 512 + swz]);
#pragma unroll
            for (int j = 0; j < 4; ++j)
                bfr[j] = *reinterpret_cast<const bf16x8*>(&sBr[(wn * 8 + j * 2 + rhi) * 512 + swz]);
#pragma unroll
            for (int i = 0; i < 4; ++i)
#pragma unroll
                for (int j = 0; j < 4; ++j)
                    acc[i][j] = __builtin_amdgcn_mfma_f32_16x16x32_bf16(af[i], bfr[j], acc[i][j], 0, 0, 0);
        }
        asm volatile("s_waitcnt vmcnt(0)" ::: "memory");
        __builtin_amdgcn_s_barrier();
    }
    __syncthreads();

    // -------- coalesced epilogue: 2 passes of 64 rows via LDS f32 tile
    float* sC = (float*)smem;        // 64 x 128 f32 = 32 KB
    int rb = (lane >> 4) * 4;
    int cb = lane & 15;
    int lrow = tid >> 2;             // 0..63
    int lcol = (tid & 3) << 5;       // 0,32,64,96
#pragma unroll
    for (int pass = 0; pass < 2; ++pass) {
        if (wm == pass) {
#pragma unroll
            for (int i = 0; i < 4; ++i)
#pragma unroll
                for (int j = 0; j < 4; ++j)
#pragma unroll
                    for (int rg = 0; rg < 4; ++rg)
                        sC[cswz(i * 16 + rb + rg, wn * 64 + j * 16 + cb)] = acc[i][j][rg];
        }
        __syncthreads();
        int gm = m0 + pass * 64 + lrow;
        if (gm < mguard) {
            int gn0 = n0 + lcol;
            float v[32];
#pragma unroll
            for (int e4 = 0; e4 < 8; ++e4) {
                float4 t = *(const float4*)&sC[cswz(lrow, lcol + e4 * 4)];
                v[e4 * 4 + 0] = t.x; v[e4 * 4 + 1] = t.y;
                v[e4 * 4 + 2] = t.z; v[e4 * 4 + 3] = t.w;
            }
            if (mode == 1 || mode == 3) {
                if (mode == 3) {
                    const float* a1 = bias + (gn0 >> 7) * 256 + (gn0 & 127);
                    const float* a2 = a1 + 128;
                    float s1 = 0.f, s2 = 0.f;
#pragma unroll
                    for (int j = 0; j < 32; ++j) {
                        s1 += v[j] * a1[j];
                        s2 += v[j] * a2[j];
                    }
                    s1 += __shfl_xor(s1, 1); s1 += __shfl_xor(s1, 2);
                    s2 += __shfl_xor(s2, 1); s2 += __shfl_xor(s2, 2);
                    if ((tid & 3) == 0) {
                        Cf[gm * 4 + (gn0 >> 7)] = s1;                    // sq
                        Cf[(size_t)MPAD * 4 + gm * 4 + (gn0 >> 7)] = s2; // sk
                    }
                }
                uint4* dst = (uint4*)(Cb + (size_t)gm * N + gn0);
#pragma unroll
                for (int q2 = 0; q2 < 4; ++q2) {
                    float s[8];
#pragma unroll
                    for (int t = 0; t < 8; ++t) {
                        float x = v[q2 * 8 + t];
                        s[t] = (mode == 1) ? gelu(x + bias[gn0 + q2 * 8 + t]) : x;
                    }
                    uint4 w;
                    w.x = (uint32_t)f2bf(s[0]) | ((uint32_t)f2bf(s[1]) << 16);
                    w.y = (uint32_t)f2bf(s[2]) | ((uint32_t)f2bf(s[3]) << 16);
                    w.z = (uint32_t)f2bf(s[4]) | ((uint32_t)f2bf(s[5]) << 16);
                    w.w = (uint32_t)f2bf(s[6]) | ((uint32_t)f2bf(s[7]) << 16);
                    dst[q2] = w;
                }
            } else {
                float4* dst = (float4*)(Cf + (size_t)gm * N + gn0);
#pragma unroll
                for (int e4 = 0; e4 < 8; ++e4) {
                    float4 t;
                    t.x = v[e4 * 4 + 0]; t.y = v[e4 * 4 + 1];
                    t.z = v[e4 * 4 + 2]; t.w = v[e4 * 4 + 3];
                    if (!first) {
                        float4 o = dst[e4];
                        t.x += o.x; t.y += o.y; t.z += o.z; t.w += o.w;
                    }
                    dst[e4] = t;
                }
            }
        }
        __syncthreads();
    }
}

// ---------------------------------------------------------------- 256xNB MFMA GEMM (FFN1: NB=256, FFN2: NB=128)
// 512 threads (8 waves, 2M x 4N). Double-buffered LDS:
//   NB=256 -> 128 KB, NB=128 -> 96 KB.
// Reads kk-outer/fi0-major: af[4] loaded once per (kk,fi0), reused across fj0.
// NO setprio (round-10/11 A/B: FFN1 77 -> 70 us without; m190 lockstep null/neg).
// mode 1: Cb bf16 = gelu(A*B + bias) (amap on A rows); mode 0: Cf fp32 = A*B.
#define QK 64

template<int NB>
__global__ __launch_bounds__(512) void k_g256(
    const ushort* __restrict__ A, const ushort* __restrict__ Bt,
    float* __restrict__ Cf, ushort* __restrict__ Cb,
    const float* __restrict__ bias,
    int N, int K, int mode, int amap)
{
    extern __shared__ ushort smem[];
    constexpr int FJ   = NB / 64;          // fj frags per wave (4 or 2)
    constexpr int BCH  = NB / 64;          // B 8-row chunks staged per wave
    constexpr int BUFU = 16384 + NB * 64;  // ushorts per buffer
    constexpr int CW   = NB / 4;           // cols per wave / per epi-thread
    constexpr int CMSK = CW - 1;           // f4-chunk XOR mask in epilogue

    int tid = threadIdx.x;
    int lane = tid & 63;
    int wave = tid >> 6;                  // 0..7
    int wr = wave >> 2;                   // 0..1  M-half
    int wc = wave & 3;                    // 0..3  N-quarter

    // XCD swizzle (both grids are multiples of 8)
    int GX = gridDim.x;
    int nwg = GX * gridDim.y;
    int bid = blockIdx.y * GX + blockIdx.x;
    int cpx = nwg >> 3;
    int wk = (bid & 7) * cpx + (bid >> 3);
    int m0 = (wk / GX) * 256;
    int n0 = (wk % GX) * NB;

    f32x4 acc[8][FJ];
#pragma unroll
    for (int i = 0; i < 8; ++i)
#pragma unroll
        for (int j = 0; j < FJ; ++j) acc[i][j] = (f32x4){0.f, 0.f, 0.f, 0.f};

    int lr = lane >> 3;                   // 0..7 row within 8-row chunk
    int gco = ((lane & 7) ^ lr) * 8;      // pre-swizzled global col offset

    const ushort* pA[4];
    const ushort* pB[BCH];
#pragma unroll
    for (int u = 0; u < 4; ++u) {
        int q = wave * 4 + u;             // 0..31 (256 A rows)
        int grA = m0 + q * 8 + lr;
        if (amap) grA = grA + 2 * (grA >> 10) + 1;
        pA[u] = A + (size_t)grA * K + gco;
    }
#pragma unroll
    for (int u = 0; u < BCH; ++u) {
        int q = wave * BCH + u;           // 0..NB/8-1 (NB B rows)
        int grB = n0 + q * 8 + lr;
        pB[u] = Bt + (size_t)grB * K + gco;
    }

    auto stage = [&](int buf) {
        ushort* sA = smem + buf * BUFU;
        ushort* sB = sA + 16384;
#pragma unroll
        for (int u = 0; u < 4; ++u) {
            int q = wave * 4 + u;
            __builtin_amdgcn_global_load_lds(
                (const __attribute__((address_space(1))) void*)pA[u],
                (__attribute__((address_space(3))) void*)&sA[q * 512], 16, 0, 0);
            pA[u] += QK;
        }
#pragma unroll
        for (int u = 0; u < BCH; ++u) {
            int q = wave * BCH + u;
            __builtin_amdgcn_global_load_lds(
                (const __attribute__((address_space(1))) void*)pB[u],
                (__attribute__((address_space(3))) void*)&sB[q * 512], 16, 0, 0);
            pB[u] += QK;
        }
    };

    const int nk = K / QK;
    stage(0);
    __syncthreads();                      // tile 0 resident

    int rr = lane & 7;
    int rhi = (lane & 15) >> 3;
    for (int t = 0; t < nk; ++t) {
        if (t + 1 < nk) stage((t + 1) & 1);   // into other buffer — safe

        const ushort* sAr = smem + (t & 1) * BUFU;
        const ushort* sBr = sAr + 16384;
#pragma unroll
        for (int kk = 0; kk < 2; ++kk) {
            int c4 = kk * 4 + (lane >> 4);
            int swz = rr * 64 + ((c4 ^ rr) << 3);
#pragma unroll
            for (int fi0 = 0; fi0 < 8; fi0 += 4) {
                bf16x8 af[4];
#pragma unroll
                for (int i = 0; i < 4; ++i) {
                    int qA = wr * 16 + (fi0 + i) * 2 + rhi;
                    af[i] = *reinterpret_cast<const bf16x8*>(&sAr[qA * 512 + swz]);
                }
#pragma unroll
                for (int fj0 = 0; fj0 < FJ; fj0 += 2) {
                    bf16x8 bfr[2];
#pragma unroll
                    for (int j = 0; j < 2; ++j) {
                        int qB = wc * (NB / 32) + (fj0 + j) * 2 + rhi;
                        bfr[j] = *reinterpret_cast<const bf16x8*>(&sBr[qB * 512 + swz]);
                    }
#pragma unroll
                    for (int i = 0; i < 4; ++i)
#pragma unroll
                        for (int j = 0; j < 2; ++j)
                            acc[fi0 + i][fj0 + j] = __builtin_amdgcn_mfma_f32_16x16x32_bf16(
                                af[i], bfr[j], acc[fi0 + i][fj0 + j], 0, 0, 0);
                }
            }
        }
        __syncthreads();                  // own stage landed + all reads done
    }

    // -------- epilogue: 2 passes of 128 rows via LDS f32 tile [128][NB]
    float* sC = (float*)smem;
    int rb = (lane >> 4) * 4;
    int cb = lane & 15;
    int lrow = tid >> 2;                  // 0..127
    int lcol = (tid & 3) * CW;
#pragma unroll
    for (int pass = 0; pass < 2; ++pass) {
        if (wr == pass) {
#pragma unroll
            for (int fi = 0; fi < 8; ++fi)
#pragma unroll
                for (int fj = 0; fj < FJ; ++fj)
#pragma unroll
                    for (int rg = 0; rg < 4; ++rg) {
                        int row = fi * 16 + rb + rg;
                        int col = wc * CW + fj * 16 + cb;
                        sC[row * NB + ((((col >> 2) ^ (row & 7)) & CMSK) << 2) + (col & 3)] =
                            acc[fi][fj][rg];
                    }
        }
        __syncthreads();
        int gm = m0 + pass * 128 + lrow;
        if (mode == 1) {
            uint4* dst = (uint4*)(Cb + (size_t)gm * N + n0 + lcol);
#pragma unroll
            for (int g = 0; g < CW / 8; ++g) {
                int col = lcol + g * 8;
                float4 a = *(const float4*)&sC[lrow * NB + ((((col >> 2) ^ (lrow & 7)) & CMSK) << 2)];
                float4 b = *(const float4*)&sC[lrow * NB + (((((col + 4) >> 2) ^ (lrow & 7)) & CMSK) << 2)];
                const float* bp = bias + n0 + col;
                float s0 = gelu(a.x + bp[0]), s1 = gelu(a.y + bp[1]);
                float s2 = gelu(a.z + bp[2]), s3 = gelu(a.w + bp[3]);
                float s4 = gelu(b.x + bp[4]), s5 = gelu(b.y + bp[5]);
                float s6 = gelu(b.z + bp[6]), s7 = gelu(b.w + bp[7]);
                uint4 w;
                w.x = (uint32_t)f2bf(s0) | ((uint32_t)f2bf(s1) << 16);
                w.y = (uint32_t)f2bf(s2) | ((uint32_t)f2bf(s3) << 16);
                w.z = (uint32_t)f2bf(s4) | ((uint32_t)f2bf(s5) << 16);
                w.w = (uint32_t)f2bf(s6) | ((uint32_t)f2bf(s7) << 16);
                dst[g] = w;
            }
        } else {
            float4* dst = (float4*)(Cf + (size_t)gm * N + n0 + lcol);
#pragma unroll
            for (int e4 = 0; e4 < CW / 4; ++e4) {
                int col = lcol + e4 * 4;
                float4 tv = *(const float4*)&sC[lrow * NB + ((((col >> 2) ^ (lrow & 7)) & CMSK) << 2)];
                dst[e4] = tv;
            }
        }
        __syncthreads();
    }
}

// ---------------------------------------------------------------- token attention + elu + residual + LN (1 wave / token, 4 waves / block)
__global__ __launch_bounds__(256) void k_attn_token(
    const ushort* __restrict__ P, const float* __restrict__ sq, const float* __restrict__ sk,
    const float* __restrict__ am, const int* __restrict__ last,
    const float* __restrict__ gam, const float* __restrict__ bet,
    ushort* __restrict__ nb)
{
    int wid = blockIdx.x * 4 + (threadIdx.x >> 6);
    int tokid = ((wid & 7) << 11) | (wid >> 3);
    int b = tokid >> 10, i = tokid & 1023;
    int lane = threadIdx.x & 63;
    int hh = lane >> 4;
    int base = b * NNODE;
    int qrow = base + 1 + i;

    int kr[13];
    int val[13];
    int rowok = am[b * SEQ + i] > 0.f ? 1 : 0;
    kr[0] = base; val[0] = rowok;
#pragma unroll
    for (int s = 0; s < 11; ++s) {
        int t = i - 5 + s;
        int inb = (t >= 0) && (t <= SEQ - 1);
        int tt = inb ? t : 0;
        int v = inb && rowok && (am[b * SEQ + tt] > 0.f);
        kr[1 + s] = base + 1 + tt;
        val[1 + s] = v;
    }
    kr[12] = base + SEQ + 1;
    val[12] = (rowok && (i >= last[b])) ? 1 : 0;

    float sqv = sq[qrow * 4 + hh];
    float sc[13];
    float mx = -1e30f;
#pragma unroll
    for (int t = 0; t < 13; ++t) {
        float s = 0.f;
        if (val[t]) {
            s = sqv + sk[kr[t] * 4 + hh];
            s = s >= 0.f ? s : 0.2f * s;
            mx = fmaxf(mx, s);
        }
        sc[t] = s;
    }
    float den = 0.f;
#pragma unroll
    for (int t = 0; t < 13; ++t) {
        float ev = 0.f;
        if (val[t]) ev = expf(sc[t] - mx);
        sc[t] = ev; den += ev;
    }
    float inv = (den > 1e-30f && den < 1e30f) ? 1.f / den : 0.f;

    int o0 = lane * 8;
    float accv[8] = {0.f, 0.f, 0.f, 0.f, 0.f, 0.f, 0.f, 0.f};
#pragma unroll
    for (int t = 0; t < 13; ++t) {
        if (val[t]) {
            float wgt = sc[t] * inv;
            const ushort* pv = P + (size_t)kr[t] * HIDN + o0;
#pragma unroll
            for (int d = 0; d < 8; ++d) accv[d] += wgt * bf2f(pv[d]);
        }
    }

    ushort* nrow = nb + (size_t)qrow * HIDN + o0;
    float x[8], s1 = 0.f, s2 = 0.f;
#pragma unroll
    for (int d = 0; d < 8; ++d) {
        float v = accv[d];
        v = v > 0.f ? v : expf(v) - 1.f;   // elu
        v += bf2f(nrow[d]);                // residual
        x[d] = v; s1 += v; s2 += v * v;
    }
#pragma unroll
    for (int off = 32; off; off >>= 1) { s1 += __shfl_xor(s1, off); s2 += __shfl_xor(s2, off); }
    float mean = s1 * (1.f / 512.f);
    float var = s2 * (1.f / 512.f) - mean * mean; var = fmaxf(var, 0.f);
    float rn = rsqrtf(var + 1e-5f);
#pragma unroll
    for (int d = 0; d < 8; ++d) {
        float y = (x[d] - mean) * rn * gam[o0 + d] + bet[o0 + d];
        nrow[d] = f2bf(y);
    }
}

// ---------------------------------------------------------------- g/l attention, split version
__global__ __launch_bounds__(256) void k_glsm(
    const float* __restrict__ sq, const float* __restrict__ sk,
    const int* __restrict__ last,
    float* __restrict__ ebuf, float* __restrict__ einv)
{
    __shared__ float red[1024];
    int rw = blockIdx.x, b = rw >> 1, isl = rw & 1;
    int base = b * NNODE;
    int qrow = base + (isl ? (SEQ + 1) : 0);
    int lastb = last[b];
    int tid = threadIdx.x;

    float sqh[4];
#pragma unroll
    for (int h = 0; h < 4; ++h) sqh[h] = sq[qrow * 4 + h];

    float mx[4] = {-1e30f, -1e30f, -1e30f, -1e30f};
    for (int j = tid; j < NNODE; j += 256) {
        bool ok = !isl || (j == 0 || j == SEQ + 1 || (j >= lastb + 1 && j <= SEQ));
        if (ok) {
#pragma unroll
            for (int h = 0; h < 4; ++h) {
                float s = sqh[h] + sk[(base + j) * 4 + h];
                s = s >= 0.f ? s : 0.2f * s;
                mx[h] = fmaxf(mx[h], s);
            }
        }
    }
#pragma unroll
    for (int h = 0; h < 4; ++h) red[tid * 4 + h] = mx[h];
    __syncthreads();
    for (int s = 128; s; s >>= 1) {
        if (tid < s) {
#pragma unroll
            for (int h = 0; h < 4; ++h)
                red[tid * 4 + h] = fmaxf(red[tid * 4 + h], red[(tid + s) * 4 + h]);
        }
        __syncthreads();
    }
#pragma unroll
    for (int h = 0; h < 4; ++h) mx[h] = red[h];
    __syncthreads();

    float sm[4] = {0.f, 0.f, 0.f, 0.f};
    for (int j = tid; j < NNODE; j += 256) {
        bool ok = !isl || (j == 0 || j == SEQ + 1 || (j >= lastb + 1 && j <= SEQ));
#pragma unroll
        for (int h = 0; h < 4; ++h) {
            float v = 0.f;
            if (ok) {
                float s = sqh[h] + sk[(base + j) * 4 + h];
                s = s >= 0.f ? s : 0.2f * s;
                v = expf(s - mx[h]);
            }
            ebuf[((size_t)rw * NNODE + j) * 4 + h] = v;
            sm[h] += v;
        }
    }
#pragma unroll
    for (int h = 0; h < 4; ++h) red[tid * 4 + h] = sm[h];
    __syncthreads();
    for (int s = 128; s; s >>= 1) {
        if (tid < s) {
#pragma unroll
            for (int h = 0; h < 4; ++h) red[tid * 4 + h] += red[(tid + s) * 4 + h];
        }
        __syncthreads();
    }
    if (tid < 4) {
        float den = red[tid];
        einv[rw * 4 + tid] = (den > 1e-30f && den < 1e30f) ? 1.f / den : 0.f;
    }
}

__global__ __launch_bounds__(256) void k_glpv(
    const ushort* __restrict__ P, const float* __restrict__ ebuf,
    float* __restrict__ pout2)
{
    __shared__ float es[JCH * 4];
    int p = blockIdx.x, rw = blockIdx.y;
    int b = rw >> 1;
    int base = b * NNODE;
    int tid = threadIdx.x;
    for (int t = tid; t < JCH * 4; t += 256)
        es[t] = ebuf[((size_t)rw * NNODE + p * JCH) * 4 + t];
    __syncthreads();
    int o0 = tid, o1 = tid + 256;
    int h0 = o0 >> 7, h1 = o1 >> 7;
    const ushort* Pb = P + (size_t)(base + p * JCH) * HIDN;
    float a0 = 0.f, a1 = 0.f;
    for (int j = 0; j < JCH; ++j) {
        const ushort* pr = Pb + (size_t)j * HIDN;
        a0 += es[j * 4 + h0] * bf2f(pr[o0]);
        a1 += es[j * 4 + h1] * bf2f(pr[o1]);
    }
    float* o = pout2 + ((size_t)rw * 9 + p) * HIDN;
    o[o0] = a0;
    o[o1] = a1;
}

__global__ __launch_bounds__(256) void k_glred(
    const float* __restrict__ pout2, const float* __restrict__ einv,
    const float* __restrict__ gam, const float* __restrict__ bet,
    ushort* __restrict__ nb)
{
    __shared__ float red[512];
    int rw = blockIdx.x, b = rw >> 1, isl = rw & 1;
    size_t qrow = (size_t)b * NNODE + (isl ? SEQ + 1 : 0);
    int tid = threadIdx.x;
    float xv[2], s1 = 0.f, s2 = 0.f;
#pragma unroll
    for (int u = 0; u < 2; ++u) {
        int o = tid + u * 256;
        int h = o >> 7;
        float acc = 0.f;
#pragma unroll
        for (int p = 0; p < 9; ++p)
            acc += pout2[((size_t)rw * 9 + p) * HIDN + o];
        acc *= einv[rw * 4 + h];
        float v = acc > 0.f ? acc : expf(acc) - 1.f;
        v += bf2f(nb[qrow * HIDN + o]);
        xv[u] = v; s1 += v; s2 += v * v;
    }
    red[tid] = s1;
    __syncthreads();
    for (int s = 128; s; s >>= 1) { if (tid < s) red[tid] += red[tid + s]; __syncthreads(); }
    float mean = red[0] * (1.f / 512.f);
    __syncthreads();
    red[tid] = s2;
    __syncthreads();
    for (int s = 128; s; s >>= 1) { if (tid < s) red[tid] += red[tid + s]; __syncthreads(); }
    float var = red[0] * (1.f / 512.f) - mean * mean; var = fmaxf(var, 0.f);
    float rn = rsqrtf(var + 1e-5f);
#pragma unroll
    for (int u = 0; u < 2; ++u) {
        int o = tid + u * 256;
        float y = (xv[u] - mean) * rn * gam[o] + bet[o];
        nb[qrow * HIDN + o] = f2bf(y);
    }
}

// ---------------------------------------------------------------- g/l FFN, parallel split version
__global__ __launch_bounds__(256) void k_fgl1(
    const ushort* __restrict__ nb, const float* __restrict__ w1,
    float* __restrict__ pmid)
{
    __shared__ float xs[64];
    int p = blockIdx.x, rw = blockIdx.y;
    int b = rw >> 1, isl = rw & 1;
    int idx = isl ? 2 : 0;
    size_t nrow = (size_t)b * NNODE + (isl ? SEQ + 1 : 0);
    int tid = threadIdx.x;
    if (tid < 64) xs[tid] = bf2f(nb[nrow * HIDN + p * 64 + tid]);
    __syncthreads();
    const float* W1 = w1 + (size_t)idx * HIDN * FFD + (size_t)p * 64 * FFD;
    float acc[8] = {0.f, 0.f, 0.f, 0.f, 0.f, 0.f, 0.f, 0.f};
    for (int ii = 0; ii < 64; ++ii) {
        float xv = xs[ii];
        const float* wrow = W1 + (size_t)ii * FFD + tid;
#pragma unroll
        for (int u = 0; u < 8; ++u) acc[u] += xv * wrow[u * 256];
    }
    float* o = pmid + ((size_t)rw * 8 + p) * FFD + tid;
#pragma unroll
    for (int u = 0; u < 8; ++u) o[u * 256] = acc[u];
}

__global__ __launch_bounds__(256) void k_fgl2(
    const float* __restrict__ pmid, const float* __restrict__ b1,
    float* __restrict__ mid)
{
    int g = blockIdx.x * 256 + threadIdx.x;
    int e4 = g * 4;
    int rw = e4 >> 11;
    int m = e4 & 2047;
    int isl = rw & 1;
    int idx = isl ? 2 : 0;
#pragma unroll
    for (int d = 0; d < 4; ++d) {
        float s = 0.f;
#pragma unroll
        for (int p = 0; p < 8; ++p)
            s += pmid[((size_t)rw * 8 + p) * FFD + m + d];
        s += b1[idx * FFD + m + d];
        mid[(size_t)rw * FFD + m + d] = gelu(s);
    }
}

__global__ __launch_bounds__(256) void k_fgl3(
    const float* __restrict__ mid, const float* __restrict__ w2,
    float* __restrict__ pout)
{
    __shared__ float ms[256];
    int p = blockIdx.x, rw = blockIdx.y;
    int isl = rw & 1;
    int idx = isl ? 2 : 0;
    int tid = threadIdx.x;
    ms[tid] = mid[(size_t)rw * FFD + p * 256 + tid];
    __syncthreads();
    const float* W2 = w2 + (size_t)idx * FFD * HIDN + (size_t)p * 256 * HIDN;
    float a0 = 0.f, a1 = 0.f;
    for (int mm = 0; mm < 256; ++mm) {
        float mv = ms[mm];
        const float* wrow = W2 + (size_t)mm * HIDN + tid;
        a0 += mv * wrow[0];
        a1 += mv * wrow[256];
    }
    float* o = pout + ((size_t)rw * 8 + p) * HIDN + tid;
    o[0] = a0;
    o[256] = a1;
}

__global__ __launch_bounds__(256) void k_fgl4(
    const float* __restrict__ pout, const float* __restrict__ b2,
    const ushort* __restrict__ nb,
    const float* __restrict__ og, const float* __restrict__ obt,
    float* __restrict__ out)
{
    __shared__ float red[512];
    int rw = blockIdx.x;
    int b = rw >> 1, isl = rw & 1;
    int idx = isl ? 2 : 0;
    size_t nrow = (size_t)b * NNODE + (isl ? SEQ + 1 : 0);
    int tid = threadIdx.x;
    float xv[2], s1 = 0.f, s2 = 0.f;
#pragma unroll
    for (int u = 0; u < 2; ++u) {
        int o = tid + u * 256;
        float s = 0.f;
#pragma unroll
        for (int p = 0; p < 8; ++p)
            s += pout[((size_t)rw * 8 + p) * HIDN + o];
        s += b2[idx * HIDN + o] + bf2f(nb[nrow * HIDN + o]);
        xv[u] = s; s1 += s; s2 += s * s;
    }
    red[tid] = s1;
    __syncthreads();
    for (int s = 128; s; s >>= 1) { if (tid < s) red[tid] += red[tid + s]; __syncthreads(); }
    float mean = red[0] * (1.f / 512.f);
    __syncthreads();
    red[tid] = s2;
    __syncthreads();
    for (int s = 128; s; s >>= 1) { if (tid < s) red[tid] += red[tid + s]; __syncthreads(); }
    float var = red[0] * (1.f / 512.f) - mean * mean; var = fmaxf(var, 0.f);
    float rn = rsqrtf(var + 1e-5f);
    size_t obase = isl ? ((size_t)8192 + (size_t)MTOK * HIDN + (size_t)b * HIDN)
                       : ((size_t)b * HIDN);
#pragma unroll
    for (int u = 0; u < 2; ++u) {
        int o = tid + u * 256;
        out[obase + o] = (xv[u] - mean) * rn * og[idx * HIDN + o] + obt[idx * HIDN + o];
    }
}

// ---------------------------------------------------------------- final token LN: in-place on Pt (fp32), + bias + residual
__global__ __launch_bounds__(64) void k_ln_final(
    float* __restrict__ Pt, const ushort* __restrict__ nb,
    const float* __restrict__ b2,
    const float* __restrict__ gam, const float* __restrict__ bet)
{
    int r = blockIdx.x, lane = threadIdx.x;
    int nrow = r + 2 * (r >> 10) + 1;
    int o0 = lane * 8;
    float* x = Pt + (size_t)r * HIDN + o0;
    const ushort* res = nb + (size_t)nrow * HIDN + o0;
    float v[8], s1 = 0.f, s2 = 0.f;
#pragma unroll
    for (int d = 0; d < 8; ++d) {
        float t = x[d] + b2[o0 + d] + bf2f(res[d]);
        v[d] = t; s1 += t; s2 += t * t;
    }
#pragma unroll
    for (int off = 32; off; off >>= 1) { s1 += __shfl_xor(s1, off); s2 += __shfl_xor(s2, off); }
    float mean = s1 * (1.f / 512.f);
    float var = s2 * (1.f / 512.f) - mean * mean; var = fmaxf(var, 0.f);
    float rn = rsqrtf(var + 1e-5f);
#pragma unroll
    for (int d = 0; d < 8; ++d)
        x[d] = (v[d] - mean) * rn * gam[o0 + d] + bet[o0 + d];
}

// ================================================================ launch
extern "C" void kernel_launch(void* const* d_in, const int* in_sizes, int n_in,
                              void* d_out, int out_size, void* d_ws, size_t ws_size,
                              hipStream_t stream)
{
    (void)in_sizes; (void)n_in; (void)out_size; (void)ws_size;
    const float* g_emb   = (const float*)d_in[0];
    const float* tok_emb = (const float*)d_in[1];
    const float* l_emb   = (const float*)d_in[2];
    const float* am      = (const float*)d_in[3];
    const int*   last    = (const int*)d_in[4];
    const float* gat_W   = (const float*)d_in[5];
    const float* gat_a   = (const float*)d_in[6];
    const float* ln_g    = (const float*)d_in[7];
    const float* ln_b    = (const float*)d_in[8];
    const float* ffn_w1  = (const float*)d_in[9];
    const float* ffn_b1  = (const float*)d_in[10];
    const float* ffn_w2  = (const float*)d_in[11];
    const float* ffn_b2  = (const float*)d_in[12];
    const float* oln_g   = (const float*)d_in[13];
    const float* oln_b   = (const float*)d_in[14];
    float* out = (float*)d_out;

    // workspace ~98 MiB (harness poisons ~268 MB of ws).
    char* w = (char*)d_ws;
    ushort* nodes_b = (ushort*)w; w += (size_t)MPAD * HIDN * 2;      // 16.9 MB
    char*   scratch = w;          w += (size_t)8 * 1024 * 1024;      //  8.0 MB (g/l scratch)
    ushort* w1t     = (ushort*)w; w += (size_t)FFD * HIDN * 2;       //  2.1 MB
    ushort* w2t     = (ushort*)w; w += (size_t)FFD * HIDN * 2;       //  2.1 MB
    ushort* gatWb   = (ushort*)w; w += (size_t)2 * HIDN * HIDN * 2;  //  1.0 MB
    float*  sqb     = (float*)w;  w += (size_t)MPAD * 4 * 4;         //  0.26 MB (sq)
    float*  skb     = (float*)w;  w += (size_t)MPAD * 4 * 4;         //  0.26 MB (sk = sqb + MPAD*4)
    ushort* Hmid    = (ushort*)w; w += (size_t)MTOK * FFD * 2;       // 67.1 MB (full FFN mid)

    // g/l FFN scratch (post-layers)
    float* pmid = (float*)scratch;
    float* mid  = pmid + (size_t)32 * 8 * FFD;
    float* pout = mid + (size_t)32 * FFD;
    // g/l attention scratch (at scratch + 3 MB; during layers)
    float* ebuf  = (float*)(scratch + (size_t)3 * 1024 * 1024);
    float* einv  = ebuf + (size_t)32 * NNODE * 4;
    float* pout2 = einv + 128;

    // P (node projections) aliases d_out (dead before outputs written).
    ushort* P = (ushort*)out;
    float* Pt = out + 8192;

    k_build_nodes<<<MPAD * HIDN / 256, 256, 0, stream>>>(g_emb, tok_emb, l_emb, nodes_b);
    k_cvt<<<(2 * HIDN * HIDN) / 256, 256, 0, stream>>>(gat_W, gatWb, 2 * HIDN * HIDN);
    k_transpose<<<dim3(FFD / 32, HIDN / 32), dim3(32, 8), 0, stream>>>(ffn_w1 + (size_t)HIDN * FFD, w1t, HIDN, FFD);
    k_transpose<<<dim3(HIDN / 32, FFD / 32), dim3(32, 8), 0, stream>>>(ffn_w2 + (size_t)FFD * HIDN, w2t, FFD, HIDN);

    for (int k = 0; k < 2; ++k) {
        // node-proj GEMM with fused sq/sk epilogue (mode 3: Cf=sqb, bias=gat_a)
        k_gemm_bt<<<dim3(HIDN / BN, MPAD / BM), 256, 0, stream>>>(
            nodes_b, gatWb + (size_t)k * HIDN * HIDN, sqb, P,
            gat_a + k * NHEAD * 2 * DHEAD,
            HIDN, HIDN, HIDN, /*mode*/3, /*amap*/0, MROWS, /*first*/1);
        k_attn_token<<<MTOK / 4, 256, 0, stream>>>(P, sqb, skb, am, last,
                                                   ln_g + k * HIDN, ln_b + k * HIDN, nodes_b);
        k_glsm<<<32, 256, 0, stream>>>(sqb, skb, last, ebuf, einv);
        k_glpv<<<dim3(9, 32), 256, 0, stream>>>(P, ebuf, pout2);
        k_glred<<<32, 256, 0, stream>>>(pout2, einv, ln_g + k * HIDN, ln_b + k * HIDN, nodes_b);
    }

    // g/l FFN (parallel split) — P (= d_out) dead from here.
    k_fgl1<<<dim3(8, 32), 256, 0, stream>>>(nodes_b, ffn_w1, pmid);
    k_fgl2<<<64, 256, 0, stream>>>(pmid, ffn_b1, mid);
    k_fgl3<<<dim3(8, 32), 256, 0, stream>>>(mid, ffn_w2, pout);
    k_fgl4<<<32, 256, 0, stream>>>(pout, ffn_b2, nodes_b, oln_g, oln_b, out);

    // token FFN. FFN1: 256x256 tile, 512 blocks.
    k_g256<256><<<dim3(FFD / 256, MTOK / 256), 512, 131072, stream>>>(
        nodes_b, w1t, nullptr, Hmid, ffn_b1 + FFD, FFD, HIDN, /*mode*/1, /*amap*/1);
    // FFN2: 256x128 tile, 256 blocks (full machine).
    k_g256<128><<<dim3(HIDN / 128, MTOK / 256), 512, 98304, stream>>>(
        Hmid, w2t, Pt, nullptr, nullptr, HIDN, FFD, /*mode*/0, /*amap*/0);
    k_ln_final<<<MTOK, 64, 0, stream>>>(Pt, nodes_b, ffn_b2 + HIDN, oln_g + HIDN, oln_b + HIDN);
}